// Round 1
// baseline (216.148 us; speedup 1.0000x reference)
//
#include <hip/hip_runtime.h>
#include <math.h>

// Problem constants: B=4, H=16, L=4096, D=64, S=128
constexpr int BB = 4;
constexpr int HH = 16;
constexpr int LL = 4096;
constexpr int DD = 64;
constexpr int SS = 128;
constexpr int BM = 128;            // rows per block

// R6: fp32 VALU GEMM floor is 27us @ 157 TF; MfmaUtil was 0. Move scores to
// MFMA via exact 2-term bf16 split: score ~= a2*b1 + a1*b2 + a1*b1 (3 MFMA
// passes, dropped a2*b2 + residuals bounded < ~2e-4 worst case). Rows whose
// top1-top2 margin < TAU are recomputed in sequential fp32 (exactly the
// ordering the previous all-fp32 kernel used, which matched reference
// bit-for-bit) -> argmax matches reference everywhere. ~0.4% rows fall back.
constexpr float TAU = 2e-3f;

typedef __attribute__((ext_vector_type(8))) short bf16x8;   // 8 bf16 = 4 VGPR
typedef __attribute__((ext_vector_type(4))) float f32x4;

#define MFMA16 __builtin_amdgcn_mfma_f32_16x16x32_bf16

__device__ __forceinline__ unsigned short f2bf(float v) {
    unsigned u = __float_as_uint(v);
    return (unsigned short)((u + 0x7fffu + ((u >> 16) & 1u)) >> 16);  // RNE
}
__device__ __forceinline__ float bf2f(unsigned short b) {
    return __uint_as_float(((unsigned)b) << 16);
}
// XOR-swizzle byte addr: spreads the 4 256B-quarters of each 1KB tile across
// bank groups; applied identically on LDS write and read (both-sides rule).
__device__ __forceinline__ unsigned swz(unsigned a) {
    return a ^ (((a >> 8) & 3u) << 5);
}
__device__ __forceinline__ void st8(unsigned char* s, unsigned a, uint2 d) {
    *(uint2*)(s + swz(a)) = d;
}
__device__ __forceinline__ bf16x8 ld8(const unsigned char* s, unsigned a) {
    return *(const bf16x8*)(s + swz(a));
}

__global__ __launch_bounds__(256) void quantizer_kernel(
    const float* __restrict__ x,   // [B,H,L,D]
    const float* __restrict__ c,   // [H,S,D]
    float* __restrict__ out,       // [B,H,L,S] one-hot
    float* __restrict__ out_c)     // [H,S,D] copy of c
{
    // Fragment store: 64 tiles x 1KB. A region [sp(2)][kt(2)][rt(8)] then
    // B region at +32768 [sp(2)][kt(2)][ct(8)]. Tile layout is fragment-major:
    // element (r,k): lane=((kin>>3)<<4)|r, byte=(kin&7)*2  (kin = k&31).
    __shared__ __align__(16) unsigned char smem[65536];
    __shared__ int amax[BM];
    __shared__ int s_nflag;
    __shared__ int s_flag[BM];
    __shared__ float s_fsc[SS];

    const int tid = threadIdx.x;
    const int blk = blockIdx.x;
    const long long r0 = (long long)blk * BM;
    const int h = (int)((r0 >> 12) & (HH - 1));   // 4096 rows per (b,h)
    const float* __restrict__ chead = c + (size_t)h * SS * DD;

    if (tid == 0) s_nflag = 0;

    // ---- stage x and c as hi/lo bf16 MFMA fragments (coalesced reads) ----
    {
        const float4* __restrict__ xg = (const float4*)(x + (size_t)r0 * DD);
        const float4* __restrict__ cg = (const float4*)chead;
        #pragma unroll
        for (int it = 0; it < 8; ++it) {
            const int idx = it * 256 + tid;     // 0..2047 == row*16 + d4
            const int d4  = idx & 15;           // float4 index along k
            const int row = idx >> 4;           // row / code 0..127
            const int kt  = d4 >> 3;            // k-step tile (k0 = d4*4)
            const int lsl = ((((d4 & 7) >> 1) << 4) | (row & 15)); // lane slot
            const int boff = (d4 & 1) * 8;      // byte offset within 16B slot
            const int t8  = row >> 4;           // rt (for x) / ct (for c)
            const unsigned bhi =
                (unsigned)((((kt << 3) | t8) << 10) + lsl * 16 + boff); // sp=0
            const unsigned blo = bhi + (16u << 10);                    // sp=1
            {
                float4 v = xg[idx];
                unsigned short h0 = f2bf(v.x), h1 = f2bf(v.y),
                               h2 = f2bf(v.z), h3 = f2bf(v.w);
                unsigned short l0 = f2bf(v.x - bf2f(h0)),
                               l1 = f2bf(v.y - bf2f(h1)),
                               l2 = f2bf(v.z - bf2f(h2)),
                               l3 = f2bf(v.w - bf2f(h3));
                st8(smem, bhi, make_uint2((unsigned)h0 | ((unsigned)h1 << 16),
                                          (unsigned)h2 | ((unsigned)h3 << 16)));
                st8(smem, blo, make_uint2((unsigned)l0 | ((unsigned)l1 << 16),
                                          (unsigned)l2 | ((unsigned)l3 << 16)));
            }
            {
                float4 v = cg[idx];
                unsigned short h0 = f2bf(v.x), h1 = f2bf(v.y),
                               h2 = f2bf(v.z), h3 = f2bf(v.w);
                unsigned short l0 = f2bf(v.x - bf2f(h0)),
                               l1 = f2bf(v.y - bf2f(h1)),
                               l2 = f2bf(v.z - bf2f(h2)),
                               l3 = f2bf(v.w - bf2f(h3));
                st8(smem, 32768u + bhi,
                    make_uint2((unsigned)h0 | ((unsigned)h1 << 16),
                               (unsigned)h2 | ((unsigned)h3 << 16)));
                st8(smem, 32768u + blo,
                    make_uint2((unsigned)l0 | ((unsigned)l1 << 16),
                               (unsigned)l2 | ((unsigned)l3 << 16)));
            }
        }
    }
    __syncthreads();

    // ---- MFMA phase: wave wv owns rows wv*32..wv*32+31 (2 row-tiles),
    //      loops all 8 col-tiles; A fragments register-resident. ----
    const int wv = tid >> 6;
    const int lane = tid & 63;
    const int ln15 = lane & 15;

    bf16x8 af[2][2][2];   // [rtb][kt][sp]
    #pragma unroll
    for (int rtb = 0; rtb < 2; ++rtb)
        #pragma unroll
        for (int kt = 0; kt < 2; ++kt)
            #pragma unroll
            for (int sp = 0; sp < 2; ++sp)
                af[rtb][kt][sp] = ld8(smem,
                    (unsigned)((((sp << 4) | (kt << 3) | (2 * wv + rtb)) << 10)
                               + lane * 16));

    float m1[2][4], m2[2][4];
    int   mi_[2][4];
    #pragma unroll
    for (int rtb = 0; rtb < 2; ++rtb)
        #pragma unroll
        for (int r = 0; r < 4; ++r) {
            m1[rtb][r] = -INFINITY; m2[rtb][r] = -INFINITY; mi_[rtb][r] = 0;
        }

    #pragma unroll
    for (int ct = 0; ct < 8; ++ct) {
        const unsigned bb = 32768u + (unsigned)(ct << 10) + (unsigned)(lane * 16);
        bf16x8 b10 = ld8(smem, bb);                 // b_hi kt0
        bf16x8 b11 = ld8(smem, bb + (1u << 13));    // b_hi kt1  (kt<<3)<<10
        bf16x8 b20 = ld8(smem, bb + (1u << 14));    // b_lo kt0  (sp<<4)<<10
        bf16x8 b21 = ld8(smem, bb + (1u << 14) + (1u << 13)); // b_lo kt1
        #pragma unroll
        for (int rtb = 0; rtb < 2; ++rtb) {
            f32x4 acc = {0.f, 0.f, 0.f, 0.f};
            acc = MFMA16(af[rtb][0][1], b10, acc, 0, 0, 0);  // a_lo * b_hi
            acc = MFMA16(af[rtb][1][1], b11, acc, 0, 0, 0);
            acc = MFMA16(af[rtb][0][0], b20, acc, 0, 0, 0);  // a_hi * b_lo
            acc = MFMA16(af[rtb][1][0], b21, acc, 0, 0, 0);
            acc = MFMA16(af[rtb][0][0], b10, acc, 0, 0, 0);  // a_hi * b_hi
            acc = MFMA16(af[rtb][1][0], b11, acc, 0, 0, 0);
            #pragma unroll
            for (int r = 0; r < 4; ++r) {
                const float v = acc[r];
                const int col = ct * 16 + ln15;
                if (v > m1[rtb][r]) {
                    m2[rtb][r] = m1[rtb][r]; m1[rtb][r] = v; mi_[rtb][r] = col;
                } else {
                    m2[rtb][r] = fmaxf(m2[rtb][r], v);  // ties -> margin 0
                }
            }
        }
    }

    // ---- per-row top-2 reduce across the 16 lanes sharing each row ----
    #pragma unroll
    for (int rtb = 0; rtb < 2; ++rtb) {
        #pragma unroll
        for (int r = 0; r < 4; ++r) {
            float a1 = m1[rtb][r], a2 = m2[rtb][r];
            int ai = mi_[rtb][r];
            #pragma unroll
            for (int off = 1; off <= 8; off <<= 1) {
                const float o1 = __shfl_xor(a1, off);
                const float o2 = __shfl_xor(a2, off);
                const int   oi = __shfl_xor(ai, off);
                const bool take = (o1 > a1) || (o1 == a1 && oi < ai);
                const float n2 = take ? fmaxf(a1, o2) : fmaxf(a2, o1);
                if (take) { a1 = o1; ai = oi; }
                a2 = n2;
            }
            if (ln15 == 0) {
                const int row = (2 * wv + rtb) * 16 + (lane >> 4) * 4 + r;
                if (a1 - a2 >= TAU) {
                    amax[row] = ai;
                } else {
                    const int p = atomicAdd(&s_nflag, 1);
                    s_flag[p] = row;
                }
            }
        }
    }
    __syncthreads();

    // ---- exact fp32 fallback for near-tie rows (sequential-k order,
    //      identical to the previous all-fp32 kernel that matched ref) ----
    const int nf = s_nflag;
    for (int f = 0; f < nf; ++f) {
        const int row = s_flag[f];
        if (tid < SS) {
            const float4* __restrict__ xr =
                (const float4*)(x + (size_t)(r0 + row) * DD);
            const float4* __restrict__ cr =
                (const float4*)(chead + (size_t)tid * DD);
            float sc = 0.f;
            #pragma unroll
            for (int q = 0; q < 16; ++q) {
                const float4 a = xr[q];
                const float4 b = cr[q];
                sc = fmaf(a.x, b.x, sc); sc = fmaf(a.y, b.y, sc);
                sc = fmaf(a.z, b.z, sc); sc = fmaf(a.w, b.w, sc);
            }
            s_fsc[tid] = sc;
        }
        __syncthreads();
        if (tid == 0) {
            float bv = s_fsc[0]; int bi = 0;
            for (int s = 1; s < SS; ++s)
                if (s_fsc[s] > bv) { bv = s_fsc[s]; bi = s; }  // first-idx wins
            amax[row] = bi;
        }
        __syncthreads();
    }

    // ---- cooperative coalesced one-hot write: 128 rows * 32 float4 ----
    float4* __restrict__ op = (float4*)(out + (size_t)r0 * SS);
    #pragma unroll 4
    for (int i = tid; i < BM * (SS / 4); i += 256) {
        const int rr = i >> 5;
        const int s0 = (i & 31) * 4;
        const int am = amax[rr];
        float4 v;
        v.x = (s0 + 0 == am) ? 1.f : 0.f;
        v.y = (s0 + 1 == am) ? 1.f : 0.f;
        v.z = (s0 + 2 == am) ? 1.f : 0.f;
        v.w = (s0 + 3 == am) ? 1.f : 0.f;
        op[i] = v;
    }

    // ---- copy c to second output region (first 128 blocks) ----
    if (blk < 128) {
        const float4* __restrict__ src = (const float4*)c;
        float4* __restrict__ dst = (float4*)out_c;
        const int idx = blk * 256 + tid;
        dst[idx] = src[idx];
    }
}

extern "C" void kernel_launch(void* const* d_in, const int* in_sizes, int n_in,
                              void* d_out, int out_size, void* d_ws, size_t ws_size,
                              hipStream_t stream) {
    const float* x = (const float*)d_in[0];   // [B,H,L,D] fp32
    const float* c = (const float*)d_in[1];   // [H,S,D]   fp32
    float* out = (float*)d_out;               // onehot [B,H,L,S] then c [H,S,D]
    float* out_c = out + (size_t)BB * HH * LL * SS;

    const int rows = BB * HH * LL;            // 262144
    const int blocks = rows / BM;             // 2048
    quantizer_kernel<<<blocks, 256, 0, stream>>>(x, c, out, out_c);
}

// Round 2
// 202.937 us; speedup vs baseline: 1.0651x; 1.0651x over previous
//
#include <hip/hip_runtime.h>
#include <math.h>

// Problem constants: B=4, H=16, L=4096, D=64, S=128
constexpr int BB = 4;
constexpr int HH = 16;
constexpr int LL = 4096;
constexpr int DD = 64;
constexpr int SS = 128;
constexpr int BM = 128;            // rows per block

// R6 post-mortem: MFMA rewrite correct (absmax 0) but latency-bound: 66KB LDS
// -> 2 blocks/CU (occupancy 17%), serial stage->MFMA->write chain, ~700
// VALU-ops/thread of bf16-split conversion. R7: (1) A fragments load global->
// reg directly (k-contiguous 16B/lane), no LDS, no staging stores; (2) B is
// pre-converted ONCE by a 64-block pre-kernel into d_ws in fragment-tile
// order, main blocks stage 32KB via async global_load_lds (zero VALU);
// (3) LDS 34KB -> 4 blocks/CU (2x occupancy); (4) trunc-hi split (1 op vs 4).
// Error bound ~2.6e-4 << TAU/2; near-tie rows still recomputed exactly.
constexpr float TAU = 2e-3f;

typedef __attribute__((ext_vector_type(8))) short bf16x8;   // 8 bf16 = 4 VGPR
typedef __attribute__((ext_vector_type(4))) float f32x4;

#define MFMA16 __builtin_amdgcn_mfma_f32_16x16x32_bf16

__device__ __forceinline__ unsigned short f2bf(float v) {
    unsigned u = __float_as_uint(v);
    return (unsigned short)((u + 0x7fffu + ((u >> 16) & 1u)) >> 16);  // RNE
}

// split 8 consecutive floats into hi (bf16 trunc) / lo (bf16 RNE of residual)
// packed 2-per-dword in element order (matches bf16x8 fragment layout).
__device__ __forceinline__ void split8(const float4 va, const float4 vb,
                                       uint4* hi, uint4* lo) {
    const float v[8] = {va.x, va.y, va.z, va.w, vb.x, vb.y, vb.z, vb.w};
    unsigned hw[4], lw[4];
    #pragma unroll
    for (int p = 0; p < 4; ++p) {
        const unsigned u0 = __float_as_uint(v[2 * p]);
        const unsigned u1 = __float_as_uint(v[2 * p + 1]);
        const unsigned h0 = u0 & 0xffff0000u;
        const unsigned h1 = u1 & 0xffff0000u;
        hw[p] = (u0 >> 16) | h1;
        lw[p] = (unsigned)f2bf(v[2 * p] - __uint_as_float(h0))
              | ((unsigned)f2bf(v[2 * p + 1] - __uint_as_float(h1)) << 16);
    }
    *hi = make_uint4(hw[0], hw[1], hw[2], hw[3]);
    *lo = make_uint4(lw[0], lw[1], lw[2], lw[3]);
}

union FragU { uint4 q; bf16x8 v; };

// ---- pre-kernel: c [H,S,D] fp32 -> ws fragment tiles, hi/lo bf16 ----
// ws layout per head (32KB): tile t=((sp<<4)|(kt<<3)|ct)*1KB; within tile
// lane l holds code ct*16+(l&15), k = kt*32+(l>>4)*8+e at byte l*16+2e.
__global__ __launch_bounds__(256) void convert_c_kernel(
    const float* __restrict__ c, unsigned char* __restrict__ ws)
{
    const int sid = blockIdx.x * 256 + threadIdx.x;  // 0..16383
    const int h  = sid >> 10;
    const int r  = sid & 1023;
    const int kt = r >> 9;
    const int ct = (r >> 6) & 7;
    const int ln = r & 63;
    const int cc = ct * 16 + (ln & 15);
    const int k0 = kt * 32 + (ln >> 4) * 8;
    const float4* src = (const float4*)(c + ((size_t)h * SS + cc) * DD + k0);
    uint4 hi, lo;
    split8(src[0], src[1], &hi, &lo);
    unsigned char* base =
        ws + (size_t)h * 32768 + (size_t)(((kt << 3) | ct) * 1024 + ln * 16);
    *(uint4*)(base) = hi;                 // sp=0 (hi) tiles
    *(uint4*)(base + 16384) = lo;         // sp=1 (lo) tiles at +16KB
}

template <bool USE_WS>
__global__ __launch_bounds__(256) void quantizer_kernel(
    const float* __restrict__ x,               // [B,H,L,D]
    const float* __restrict__ c,               // [H,S,D]
    const unsigned char* __restrict__ ws,      // pre-converted B tiles
    float* __restrict__ out,                   // [B,H,L,S] one-hot
    float* __restrict__ out_c)                 // [H,S,D] copy of c
{
    __shared__ __align__(16) unsigned char smemB[32768];  // B tiles only
    __shared__ int amax[BM];
    __shared__ int s_nflag;
    __shared__ int s_flag[BM];
    __shared__ float s_fsc[SS];

    const int tid = threadIdx.x;
    const int wv = tid >> 6;
    const int lane = tid & 63;
    const int ln15 = lane & 15;
    const int blk = blockIdx.x;
    const long long r0 = (long long)blk * BM;
    const int h = (int)((r0 >> 12) & (HH - 1));   // 4096 rows per (b,h)
    const float* __restrict__ chead = c + (size_t)h * SS * DD;

    if (tid == 0) s_nflag = 0;

    // ---- stage B tiles into LDS ----
    if (USE_WS) {
        // async DMA, fragment order already materialized in ws; LDS dest is
        // wave-uniform base + lane*16 (linear) == exactly the tile layout.
        const unsigned char* wsb = ws + (size_t)h * 32768;
        #pragma unroll
        for (int it = 0; it < 8; ++it) {
            const unsigned off = (unsigned)(wv * 8192 + it * 1024);
            __builtin_amdgcn_global_load_lds(
                (const __attribute__((address_space(1))) unsigned*)
                    (wsb + off + (unsigned)(lane * 16)),
                (__attribute__((address_space(3))) unsigned*)(smemB + off),
                16, 0, 0);
        }
    } else {
        // fallback: convert in-block (slot order -> contiguous LDS writes)
        #pragma unroll
        for (int it = 0; it < 4; ++it) {
            const int sid = it * 256 + tid;        // 0..1023
            const int kt = sid >> 9;
            const int ct = (sid >> 6) & 7;
            const int ln = sid & 63;
            const int cc = ct * 16 + (ln & 15);
            const int k0 = kt * 32 + (ln >> 4) * 8;
            const float4* src = (const float4*)(chead + (size_t)cc * DD + k0);
            uint4 hi, lo;
            split8(src[0], src[1], &hi, &lo);
            unsigned char* dst = smemB + ((kt << 3) | ct) * 1024 + ln * 16;
            *(uint4*)dst = hi;
            *(uint4*)(dst + 16384) = lo;
        }
    }

    // ---- A fragments: global -> registers, split in-reg (no LDS) ----
    // lane l covers row (l&15) of its 16-row tile, k=(l>>4)*8..+7 — 2x16B
    // k-contiguous per (rtb,kt). Wave touches a full 4KB contiguous span.
    bf16x8 af[2][2][2];   // [rtb][kt][sp]  sp0=hi sp1=lo
    #pragma unroll
    for (int rtb = 0; rtb < 2; ++rtb) {
        const size_t row = (size_t)(r0 + wv * 32 + rtb * 16 + ln15);
        const float* xr = x + row * DD + (lane >> 4) * 8;
        #pragma unroll
        for (int kt = 0; kt < 2; ++kt) {
            const float4* s4 = (const float4*)(xr + kt * 32);
            FragU hi, lo;
            split8(s4[0], s4[1], &hi.q, &lo.q);
            af[rtb][kt][0] = hi.v;
            af[rtb][kt][1] = lo.v;
        }
    }
    __syncthreads();   // drains vmcnt (global_load_lds) before ds_read

    // ---- MFMA phase: wave owns 32 rows (2 tiles), loops 8 col-tiles ----
    float m1[2][4], m2[2][4];
    int   mi_[2][4];
    #pragma unroll
    for (int rtb = 0; rtb < 2; ++rtb)
        #pragma unroll
        for (int r = 0; r < 4; ++r) {
            m1[rtb][r] = -INFINITY; m2[rtb][r] = -INFINITY; mi_[rtb][r] = 0;
        }

    #pragma unroll
    for (int ct = 0; ct < 8; ++ct) {
        const unsigned bb = (unsigned)(ct << 10) + (unsigned)(lane * 16);
        const bf16x8 b10 = *(const bf16x8*)(smemB + bb);           // hi kt0
        const bf16x8 b11 = *(const bf16x8*)(smemB + bb + 8192);    // hi kt1
        const bf16x8 b20 = *(const bf16x8*)(smemB + bb + 16384);   // lo kt0
        const bf16x8 b21 = *(const bf16x8*)(smemB + bb + 24576);   // lo kt1
        #pragma unroll
        for (int rtb = 0; rtb < 2; ++rtb) {
            f32x4 acc = {0.f, 0.f, 0.f, 0.f};
            acc = MFMA16(af[rtb][0][1], b10, acc, 0, 0, 0);  // a_lo * b_hi
            acc = MFMA16(af[rtb][1][1], b11, acc, 0, 0, 0);
            acc = MFMA16(af[rtb][0][0], b20, acc, 0, 0, 0);  // a_hi * b_lo
            acc = MFMA16(af[rtb][1][0], b21, acc, 0, 0, 0);
            acc = MFMA16(af[rtb][0][0], b10, acc, 0, 0, 0);  // a_hi * b_hi
            acc = MFMA16(af[rtb][1][0], b11, acc, 0, 0, 0);
            #pragma unroll
            for (int r = 0; r < 4; ++r) {
                const float v = acc[r];
                const int col = ct * 16 + ln15;
                if (v > m1[rtb][r]) {
                    m2[rtb][r] = m1[rtb][r]; m1[rtb][r] = v; mi_[rtb][r] = col;
                } else {
                    m2[rtb][r] = fmaxf(m2[rtb][r], v);  // ties -> margin 0
                }
            }
        }
    }

    // ---- per-row top-2 reduce across the 16 lanes sharing each row ----
    #pragma unroll
    for (int rtb = 0; rtb < 2; ++rtb) {
        #pragma unroll
        for (int r = 0; r < 4; ++r) {
            float a1 = m1[rtb][r], a2 = m2[rtb][r];
            int ai = mi_[rtb][r];
            #pragma unroll
            for (int off = 1; off <= 8; off <<= 1) {
                const float o1 = __shfl_xor(a1, off);
                const float o2 = __shfl_xor(a2, off);
                const int   oi = __shfl_xor(ai, off);
                const bool take = (o1 > a1) || (o1 == a1 && oi < ai);
                const float n2 = take ? fmaxf(a1, o2) : fmaxf(a2, o1);
                if (take) { a1 = o1; ai = oi; }
                a2 = n2;
            }
            if (ln15 == 0) {
                const int row = (2 * wv + rtb) * 16 + (lane >> 4) * 4 + r;
                if (a1 - a2 >= TAU) {
                    amax[row] = ai;
                } else {
                    const int p = atomicAdd(&s_nflag, 1);
                    s_flag[p] = row;
                }
            }
        }
    }
    __syncthreads();

    // ---- exact fp32 fallback for near-tie rows (sequential-k order,
    //      identical to the all-fp32 kernel that matched ref exactly) ----
    const int nf = s_nflag;
    for (int f = 0; f < nf; ++f) {
        const int row = s_flag[f];
        if (tid < SS) {
            const float4* __restrict__ xr =
                (const float4*)(x + (size_t)(r0 + row) * DD);
            const float4* __restrict__ cr =
                (const float4*)(chead + (size_t)tid * DD);
            float sc = 0.f;
            #pragma unroll
            for (int q = 0; q < 16; ++q) {
                const float4 a = xr[q];
                const float4 b = cr[q];
                sc = fmaf(a.x, b.x, sc); sc = fmaf(a.y, b.y, sc);
                sc = fmaf(a.z, b.z, sc); sc = fmaf(a.w, b.w, sc);
            }
            s_fsc[tid] = sc;
        }
        __syncthreads();
        if (tid == 0) {
            float bv = s_fsc[0]; int bi = 0;
            for (int s = 1; s < SS; ++s)
                if (s_fsc[s] > bv) { bv = s_fsc[s]; bi = s; }  // first-idx wins
            amax[row] = bi;
        }
        __syncthreads();
    }

    // ---- cooperative coalesced one-hot write: 128 rows * 32 float4 ----
    float4* __restrict__ op = (float4*)(out + (size_t)r0 * SS);
    #pragma unroll 4
    for (int i = tid; i < BM * (SS / 4); i += 256) {
        const int rr = i >> 5;
        const int s0 = (i & 31) * 4;
        const int am = amax[rr];
        float4 v;
        v.x = (s0 + 0 == am) ? 1.f : 0.f;
        v.y = (s0 + 1 == am) ? 1.f : 0.f;
        v.z = (s0 + 2 == am) ? 1.f : 0.f;
        v.w = (s0 + 3 == am) ? 1.f : 0.f;
        op[i] = v;
    }

    // ---- copy c to second output region (first 128 blocks) ----
    if (blk < 128) {
        const float4* __restrict__ src = (const float4*)c;
        float4* __restrict__ dst = (float4*)out_c;
        const int idx = blk * 256 + tid;
        dst[idx] = src[idx];
    }
}

extern "C" void kernel_launch(void* const* d_in, const int* in_sizes, int n_in,
                              void* d_out, int out_size, void* d_ws, size_t ws_size,
                              hipStream_t stream) {
    const float* x = (const float*)d_in[0];   // [B,H,L,D] fp32
    const float* c = (const float*)d_in[1];   // [H,S,D]   fp32
    float* out = (float*)d_out;               // onehot [B,H,L,S] then c [H,S,D]
    float* out_c = out + (size_t)BB * HH * LL * SS;

    const int rows = BB * HH * LL;            // 262144
    const int blocks = rows / BM;             // 2048
    const size_t ws_need = (size_t)HH * 32768; // 512 KB

    if (d_ws != nullptr && ws_size >= ws_need) {
        convert_c_kernel<<<64, 256, 0, stream>>>(c, (unsigned char*)d_ws);
        quantizer_kernel<true><<<blocks, 256, 0, stream>>>(
            x, c, (const unsigned char*)d_ws, out, out_c);
    } else {
        quantizer_kernel<false><<<blocks, 256, 0, stream>>>(
            x, c, nullptr, out, out_c);
    }
}